// Round 1
// baseline (1400.099 us; speedup 1.0000x reference)
//
#include <hip/hip_runtime.h>
#include <math.h>

#define TT 64
#define BB 64
#define DD 512
#define HH 512
#define G4 2048
#define OO 128

// ---------------- Phase A: G[t,b,j] = x_t @ Wih_t^T + b_ih + b_hh ----------------
// grid (32 j-tiles, 64 t), 256 threads. 64x64 tile, K=512 in 32-chunks.
__global__ __launch_bounds__(256) void phaseA(const float* __restrict__ x,
                                              const float* __restrict__ wih,
                                              const float* __restrict__ bih,
                                              const float* __restrict__ bhh,
                                              float* __restrict__ Gb,
                                              float* __restrict__ hb,
                                              float* __restrict__ cbuf) {
  int tid = threadIdx.x;
  int t = blockIdx.y;
  int j0 = blockIdx.x * 64;

  // zero h buffer 0 and c buffer (initial state)
  int gtid = (blockIdx.y * gridDim.x + blockIdx.x) * 256 + tid;
  if (gtid < BB * HH) { hb[gtid] = 0.f; cbuf[gtid] = 0.f; }

  __shared__ float Xs[64][36];   // padded for float4 reads along k
  __shared__ float Wsh[64][33];  // padded for scalar reads

  float acc[4][4];
#pragma unroll
  for (int i = 0; i < 4; i++)
#pragma unroll
    for (int j = 0; j < 4; j++) acc[i][j] = 0.f;

  int tx = tid & 15, ty = tid >> 4;
  const float* xb = x + (size_t)t * (BB * DD);
  const float* wb = wih + (size_t)t * (G4 * DD) + (size_t)j0 * DD;

  for (int k0 = 0; k0 < DD; k0 += 32) {
    for (int i = tid; i < 64 * 8; i += 256) {
      int r = i >> 3, c4 = (i & 7) << 2;
      float4 v = *(const float4*)(xb + r * DD + k0 + c4);
      *(float4*)(&Xs[r][c4]) = v;
    }
    for (int i = tid; i < 64 * 8; i += 256) {
      int r = i >> 3, c4 = (i & 7) << 2;
      float4 v = *(const float4*)(wb + r * DD + k0 + c4);
      Wsh[r][c4] = v.x; Wsh[r][c4 + 1] = v.y; Wsh[r][c4 + 2] = v.z; Wsh[r][c4 + 3] = v.w;
    }
    __syncthreads();
#pragma unroll
    for (int k = 0; k < 32; k += 4) {
      float4 a4[4];
#pragma unroll
      for (int i = 0; i < 4; i++) a4[i] = *(const float4*)(&Xs[ty * 4 + i][k]);
#pragma unroll
      for (int j = 0; j < 4; j++) {
        float w0 = Wsh[tx * 4 + j][k];
        float w1 = Wsh[tx * 4 + j][k + 1];
        float w2 = Wsh[tx * 4 + j][k + 2];
        float w3 = Wsh[tx * 4 + j][k + 3];
#pragma unroll
        for (int i = 0; i < 4; i++)
          acc[i][j] += a4[i].x * w0 + a4[i].y * w1 + a4[i].z * w2 + a4[i].w * w3;
      }
    }
    __syncthreads();
  }

  const float* bi = bih + t * G4 + j0;
  const float* bh2 = bhh + t * G4 + j0;
  float bias[4];
#pragma unroll
  for (int j = 0; j < 4; j++) {
    int jj = tx * 4 + j;
    bias[j] = bi[jj] + bh2[jj];
  }
#pragma unroll
  for (int i = 0; i < 4; i++) {
    int b = ty * 4 + i;
    float4 o;
    o.x = acc[i][0] + bias[0];
    o.y = acc[i][1] + bias[1];
    o.z = acc[i][2] + bias[2];
    o.w = acc[i][3] + bias[3];
    *(float4*)(&Gb[((size_t)t * BB + b) * G4 + j0 + tx * 4]) = o;
  }
}

__device__ __forceinline__ float sigm(float v) { return 1.f / (1.f + expf(-v)); }

// ---------------- Phase B: one timestep ----------------
// grid 256 blocks x 256 threads. Block g owns hidden units {2g, 2g+1}:
// 8 Whh rows j = q*512 + 2g + kk  (q = gate, kk = which unit).
// thread = (b4 in [0,16), kk in {0,1}, kq in [0,8)): 4 batches x 4 gates, k-range 64.
__global__ __launch_bounds__(256) void stepK(const float* __restrict__ whh,
                                             const float* __restrict__ Gb,
                                             const int* __restrict__ lengths,
                                             float* __restrict__ hb,
                                             float* __restrict__ cbuf,
                                             float* __restrict__ hf, int t) {
  __shared__ float Wsf[8 * 544];  // 8 rows, swizzled: col' = c + (c>>6)*4
  int tid = threadIdx.x;
  int g = blockIdx.x;
  const float* hold = hb + (t & 1) * (BB * HH);
  float* hnew = hb + ((t + 1) & 1) * (BB * HH);
  const float* wt = whh + (size_t)t * (G4 * HH);

  for (int i = tid; i < 8 * 128; i += 256) {
    int r = i >> 7, c = (i & 127) << 2;
    int q = r >> 1, kk = r & 1;
    int j = q * 512 + 2 * g + kk;
    float4 v = *(const float4*)(wt + (size_t)j * HH + c);
    int col = c + ((c >> 6) << 2);
    *(float4*)(&Wsf[r * 544 + col]) = v;
  }
  __syncthreads();

  int kq = tid & 7;
  int kk = (tid >> 3) & 1;
  int b4 = tid >> 4;
  int bbase = b4 << 2;
  int kbase = kq << 6;
  int swz = kq << 2;

  float acc[4][4];  // [b][q]
#pragma unroll
  for (int i = 0; i < 4; i++)
#pragma unroll
    for (int q = 0; q < 4; q++) acc[i][q] = 0.f;

#pragma unroll
  for (int ki = 0; ki < 16; ki++) {
    int k = kbase + (ki << 2);
    float4 h0 = *(const float4*)(hold + (bbase + 0) * HH + k);
    float4 h1 = *(const float4*)(hold + (bbase + 1) * HH + k);
    float4 h2 = *(const float4*)(hold + (bbase + 2) * HH + k);
    float4 h3 = *(const float4*)(hold + (bbase + 3) * HH + k);
#pragma unroll
    for (int q = 0; q < 4; q++) {
      float4 w = *(const float4*)(&Wsf[(q * 2 + kk) * 544 + k + swz]);
      acc[0][q] += h0.x * w.x + h0.y * w.y + h0.z * w.z + h0.w * w.w;
      acc[1][q] += h1.x * w.x + h1.y * w.y + h1.z * w.z + h1.w * w.w;
      acc[2][q] += h2.x * w.x + h2.y * w.y + h2.z * w.z + h2.w * w.w;
      acc[3][q] += h3.x * w.x + h3.y * w.y + h3.z * w.z + h3.w * w.w;
    }
  }
  // reduce partial sums across the 8 kq lanes (tid bits 0..2)
#pragma unroll
  for (int m = 1; m <= 4; m <<= 1)
#pragma unroll
    for (int i = 0; i < 4; i++)
#pragma unroll
      for (int q = 0; q < 4; q++) acc[i][q] += __shfl_xor(acc[i][q], m);

  if (kq < 4) {
    int b = bbase + kq;
    int ku = 2 * g + kk;
    const float* gp = Gb + ((size_t)t * BB + b) * G4 + ku;
    float gi = acc[kq][0] + gp[0];
    float gf = acc[kq][1] + gp[512];
    float gg = acc[kq][2] + gp[1024];
    float go = acc[kq][3] + gp[1536];
    float iv = sigm(gi), fv = sigm(gf), gv = tanhf(gg), ov = sigm(go);
    int ci = b * HH + ku;
    float cv = fv * cbuf[ci] + iv * gv;
    cbuf[ci] = cv;
    float hv = ov * tanhf(cv);
    hnew[ci] = hv;
    if (lengths[b] - 1 == t) hf[ci] = hv;
  }
}

// ---------------- Final: logits = hf @ w_ho^T + b_ho, then log_softmax ----------------
__global__ __launch_bounds__(128) void finalK(const float* __restrict__ hf,
                                              const float* __restrict__ who,
                                              const float* __restrict__ bho,
                                              float* __restrict__ out) {
  int b = blockIdx.x, o = threadIdx.x;
  const float* h = hf + b * HH;
  const float* w = who + o * HH;
  float s = bho[o];
#pragma unroll 4
  for (int k = 0; k < HH; k += 4) {
    float4 hv = *(const float4*)(h + k);
    float4 wv = *(const float4*)(w + k);
    s += hv.x * wv.x + hv.y * wv.y + hv.z * wv.z + hv.w * wv.w;
  }
  __shared__ float red[2];
  __shared__ float red2[2];
  float m = s;
#pragma unroll
  for (int msk = 32; msk; msk >>= 1) m = fmaxf(m, __shfl_xor(m, msk));
  int wave = o >> 6;
  if ((o & 63) == 0) red[wave] = m;
  __syncthreads();
  m = fmaxf(red[0], red[1]);
  float e = expf(s - m);
#pragma unroll
  for (int msk = 32; msk; msk >>= 1) e += __shfl_xor(e, msk);
  if ((o & 63) == 0) red2[wave] = e;
  __syncthreads();
  float sum = red2[0] + red2[1];
  out[b * OO + o] = (s - m) - logf(sum);
}

extern "C" void kernel_launch(void* const* d_in, const int* in_sizes, int n_in,
                              void* d_out, int out_size, void* d_ws, size_t ws_size,
                              hipStream_t stream) {
  const float* x = (const float*)d_in[0];
  const float* wih = (const float*)d_in[1];
  const float* whh = (const float*)d_in[2];
  const float* bih = (const float*)d_in[3];
  const float* bhh = (const float*)d_in[4];
  const float* who = (const float*)d_in[5];
  const float* bho = (const float*)d_in[6];
  const int* lengths = (const int*)d_in[7];
  float* out = (float*)d_out;

  float* ws = (float*)d_ws;
  float* Gb = ws;                               // 64*64*2048 = 8388608 floats
  float* hb = Gb + (size_t)TT * BB * G4;        // 2*64*512
  float* cb = hb + 2 * BB * HH;                 // 64*512
  float* hf = cb + BB * HH;                     // 64*512

  dim3 gA(32, 64);
  phaseA<<<gA, 256, 0, stream>>>(x, wih, bih, bhh, Gb, hb, cb);
  for (int t = 0; t < TT; t++)
    stepK<<<256, 256, 0, stream>>>(whh, Gb, lengths, hb, cb, hf, t);
  finalK<<<BB, 128, 0, stream>>>(hf, who, bho, out);
}